// Round 1
// baseline (28.785 us; speedup 1.0000x reference)
//
#include <hip/hip_runtime.h>

// Problem constants (from setup_inputs): B=32, P=512, D=384, max_len=2048.
#define LR_B      32
#define LR_P      512
#define LR_D      384
#define LR_MAXLEN 2048
#define LR_V4     (LR_D / 4)   // 96 float4 per row

// Kernel 1: per-batch inclusive scan of durations -> ends[]; write mel_len
// (as FLOAT, since the harness reads the whole output buffer as float32);
// binary-search the phoneme index for each of the 2048 output frames.
__global__ __launch_bounds__(LR_P) void lr_scan_idx(
    const int* __restrict__ dur,   // [B][P]
    int* __restrict__ idx_out,     // [B][MAXLEN], -1 = masked (zero row)
    float* __restrict__ mel_out)   // [B], float-encoded mel_lens
{
    const int b   = blockIdx.x;
    const int tid = threadIdx.x;

    __shared__ int s[LR_P];
    s[tid] = dur[b * LR_P + tid];
    __syncthreads();

    // Hillis-Steele inclusive scan over 512 elements (9 steps).
    #pragma unroll
    for (int off = 1; off < LR_P; off <<= 1) {
        int v = (tid >= off) ? s[tid - off] : 0;
        __syncthreads();
        s[tid] += v;
        __syncthreads();
    }

    const int mel = s[LR_P - 1];      // total length, <= 2048 by construction
    if (tid == 0) mel_out[b] = (float)mel;

    // Each thread resolves 4 frames: t, t+512, t+1024, t+1536.
    #pragma unroll
    for (int k = 0; k < LR_MAXLEN / LR_P; ++k) {
        const int t = tid + k * LR_P;
        int r;
        if (t >= mel) {
            r = -1;  // masked: output row is zeros
        } else {
            // searchsorted(ends, t, side='right'): first i with ends[i] > t.
            int lo = 0, hi = LR_P;
            while (lo < hi) {
                int mid = (lo + hi) >> 1;
                if (s[mid] <= t) lo = mid + 1; else hi = mid;
            }
            r = lo;  // t < mel == ends[P-1] guarantees lo < P
        }
        idx_out[b * LR_MAXLEN + t] = r;
    }
}

// Kernel 2: one thread per output float4. frame = gid/96; gather or zero.
__global__ __launch_bounds__(256) void lr_gather(
    const float4* __restrict__ x4,    // [B][P][V4]
    const int*    __restrict__ idx,   // [B][MAXLEN]
    float4*       __restrict__ out4)  // [B][MAXLEN][V4]
{
    const int gid   = blockIdx.x * 256 + threadIdx.x;
    const int frame = gid / LR_V4;             // magic-mul division
    const int v     = gid - frame * LR_V4;

    const int p = idx[frame];                  // broadcast within 96-thread group
    float4 val;
    if (p >= 0) {
        const int b = frame >> 11;             // frame / 2048
        val = x4[(b * LR_P + p) * LR_V4 + v];
    } else {
        val = make_float4(0.f, 0.f, 0.f, 0.f);
    }
    out4[gid] = val;
}

extern "C" void kernel_launch(void* const* d_in, const int* in_sizes, int n_in,
                              void* d_out, int out_size, void* d_ws, size_t ws_size,
                              hipStream_t stream)
{
    const float* x   = (const float*)d_in[0];  // [B][P][D] float32
    const int*   dur = (const int*)d_in[1];    // [B][P] int32
    // d_in[2] = max_len scalar (2048), compile-time constant here.

    float* out = (float*)d_out;                          // [B][MAXLEN][D]
    float* mel = out + (size_t)LR_B * LR_MAXLEN * LR_D;  // [B] float-encoded

    int* ws_idx = (int*)d_ws;                  // [B][MAXLEN] = 256 KiB

    lr_scan_idx<<<LR_B, LR_P, 0, stream>>>(dur, ws_idx, mel);

    const int total4 = LR_B * LR_MAXLEN * LR_V4;         // 6,291,456
    lr_gather<<<total4 / 256, 256, 0, stream>>>(
        (const float4*)x, ws_idx, (float4*)out);
}

// Round 3
// 26.744 us; speedup vs baseline: 1.0763x; 1.0763x over previous
//
#include <hip/hip_runtime.h>

// Problem constants (from setup_inputs): B=32, P=512, D=384, max_len=2048.
#define LR_B      32
#define LR_P      512
#define LR_D      384
#define LR_MAXLEN 2048
#define LR_V4     (LR_D / 4)     // 96 float4 per row
#define LR_HV4    (LR_V4 / 2)    // 48: each gather thread does v0 and v0+48

// Native clang vector type — required by __builtin_nontemporal_store
// (HIP's float4 is a struct and is rejected).
typedef float f32x4 __attribute__((ext_vector_type(4)));

// ---------------------------------------------------------------------------
// Kernel 1: per-batch inclusive scan of durations -> ends[]; mel_len as FLOAT
// (harness reads the whole output as float32); binary-search phoneme index
// for each of the 2048 output frames. 32 blocks, latency-bound — minimize
// barriers via wave-shuffle scan (2 barriers total).
// ---------------------------------------------------------------------------
__global__ __launch_bounds__(LR_P) void lr_scan_idx(
    const int* __restrict__ dur,   // [B][P]
    int* __restrict__ idx_out,     // [B][MAXLEN], -1 = masked (zero row)
    float* __restrict__ mel_out)   // [B], float-encoded mel_lens
{
    const int b    = blockIdx.x;
    const int tid  = threadIdx.x;
    const int lane = tid & 63;
    const int wid  = tid >> 6;     // 8 waves

    __shared__ int ends[LR_P];
    __shared__ int wsum[LR_P / 64];

    int v = dur[b * LR_P + tid];

    // Inclusive scan within the wave (6 shuffle steps, no barriers).
    #pragma unroll
    for (int off = 1; off < 64; off <<= 1) {
        int u = __shfl_up(v, off, 64);
        if (lane >= off) v += u;
    }
    if (lane == 63) wsum[wid] = v;
    __syncthreads();

    // Add exclusive sum of preceding wave totals (8 values, LDS broadcast).
    int woff = 0;
    #pragma unroll
    for (int i = 0; i < LR_P / 64; ++i)
        woff += (i < wid) ? wsum[i] : 0;
    v += woff;
    ends[tid] = v;
    __syncthreads();

    const int mel = ends[LR_P - 1];           // total length (<= 2048)
    if (tid == 0) mel_out[b] = (float)mel;

    // Each thread resolves 4 frames: t, t+512, t+1024, t+1536.
    #pragma unroll
    for (int k = 0; k < LR_MAXLEN / LR_P; ++k) {
        const int t = tid + k * LR_P;
        int r;
        if (t >= mel) {
            r = -1;                            // masked: zero row
        } else {
            // searchsorted(ends, t, 'right'): first i with ends[i] > t.
            int lo = 0, hi = LR_P;
            while (lo < hi) {
                int mid = (lo + hi) >> 1;
                if (ends[mid] <= t) lo = mid + 1; else hi = mid;
            }
            r = lo;                            // t < mel guarantees lo < P
        }
        idx_out[b * LR_MAXLEN + t] = r;
    }
}

// ---------------------------------------------------------------------------
// Kernel 2: gather. Each thread handles 2 float4 (v0 and v0+48) of one frame.
// Grid is XCD-chunk-swizzled so each XCD owns 4 consecutive batches:
// x footprint/XCD = 3.1 MB < 4 MB L2, so row re-reads across consecutive
// frames hit L2 instead of re-fetching HBM. Output stream uses nontemporal
// stores to avoid evicting x from L2.
// ---------------------------------------------------------------------------
#define LR_GBLOCKS ((LR_B * LR_MAXLEN * LR_HV4) / 256)   // 12288
#define LR_NXCD    8
#define LR_CHUNK   (LR_GBLOCKS / LR_NXCD)                // 1536

__global__ __launch_bounds__(256) void lr_gather(
    const f32x4* __restrict__ x4,    // [B][P][V4]
    const int*   __restrict__ idx,   // [B][MAXLEN]
    f32x4*       __restrict__ out4)  // [B][MAXLEN][V4]
{
    // Bijective chunked XCD swizzle: physical blocks {k, k+8, k+16, ...}
    // (all on XCD k) take logical ids k*CHUNK, k*CHUNK+1, ...
    const int bid = blockIdx.x;
    const int lb  = (bid & (LR_NXCD - 1)) * LR_CHUNK + (bid >> 3);

    const int gid   = lb * 256 + threadIdx.x;   // [0, B*MAXLEN*48)
    const int frame = gid / LR_HV4;             // magic-mul division
    const int v0    = gid - frame * LR_HV4;     // [0, 48)

    const int p = idx[frame];                   // broadcast within 48-thread group
    f32x4 a, c;
    if (p >= 0) {
        const int b    = frame >> 11;           // frame / 2048
        const int base = (b * LR_P + p) * LR_V4 + v0;
        a = x4[base];
        c = x4[base + LR_HV4];
    } else {
        a = (f32x4){0.f, 0.f, 0.f, 0.f};
        c = a;
    }
    const int obase = frame * LR_V4 + v0;
    __builtin_nontemporal_store(a, &out4[obase]);
    __builtin_nontemporal_store(c, &out4[obase + LR_HV4]);
}

extern "C" void kernel_launch(void* const* d_in, const int* in_sizes, int n_in,
                              void* d_out, int out_size, void* d_ws, size_t ws_size,
                              hipStream_t stream)
{
    const float* x   = (const float*)d_in[0];  // [B][P][D] float32
    const int*   dur = (const int*)d_in[1];    // [B][P] int32
    // d_in[2] = max_len scalar (2048), compile-time constant here.

    float* out = (float*)d_out;                          // [B][MAXLEN][D]
    float* mel = out + (size_t)LR_B * LR_MAXLEN * LR_D;  // [B] float-encoded

    int* ws_idx = (int*)d_ws;                  // [B][MAXLEN] = 256 KiB

    lr_scan_idx<<<LR_B, LR_P, 0, stream>>>(dur, ws_idx, mel);

    lr_gather<<<LR_GBLOCKS, 256, 0, stream>>>(
        (const f32x4*)x, ws_idx, (f32x4*)out);
}

// Round 4
// 25.232 us; speedup vs baseline: 1.1408x; 1.0599x over previous
//
#include <hip/hip_runtime.h>

// Problem constants (from setup_inputs): B=32, P=512, D=384, max_len=2048.
#define LR_B      32
#define LR_P      512
#define LR_D      384
#define LR_MAXLEN 2048
#define LR_V4     (LR_D / 4)       // 96 float4 per row
#define LR_FPB    32               // frames per block
#define LR_F4PB   (LR_FPB * LR_V4) // 3072 float4 per block
#define LR_THREADS 256
#define LR_F4PT   (LR_F4PB / LR_THREADS)  // 12 float4 per thread

#define LR_CHUNKS  (LR_MAXLEN / LR_FPB)        // 64 chunks per batch
#define LR_GBLOCKS (LR_B * LR_CHUNKS)          // 2048 blocks
#define LR_NXCD    8
#define LR_CPX     (LR_GBLOCKS / LR_NXCD)      // 256 blocks per XCD

// Native clang vector type — required by __builtin_nontemporal_store.
typedef float f32x4 __attribute__((ext_vector_type(4)));

// ---------------------------------------------------------------------------
// Fully fused kernel. Each block owns 32 consecutive frames of one batch:
//   1. load the batch's 512 durations (2 per thread, int2),
//   2. wave-shuffle inclusive scan (2 barriers total, no binary search),
//   3. SCATTER: each thread writes its own 2 phonemes' ids into the block's
//      32-entry frame->phoneme window (intervals partition [0,mel), dur<=4),
//   4. gather 12 float4 per thread, nontemporal-store the output stream.
// XCD-chunk swizzle: each XCD owns 4 consecutive batches -> x footprint
// 3.1 MB < 4 MB L2, so row re-reads are L2 hits.
// ---------------------------------------------------------------------------
__global__ __launch_bounds__(LR_THREADS) void lr_fused(
    const int*   __restrict__ dur,   // [B][P]
    const f32x4* __restrict__ x4,    // [B][P][V4]
    f32x4*       __restrict__ out4,  // [B][MAXLEN][V4]
    float*       __restrict__ mel_out) // [B], float-encoded
{
    // Bijective chunked XCD swizzle (2048 % 8 == 0).
    const int bid = blockIdx.x;
    const int lb  = (bid & (LR_NXCD - 1)) * LR_CPX + (bid >> 3);

    const int b    = lb >> 6;           // lb / 64 : batch
    const int c    = lb & 63;           // chunk within batch
    const int base = c * LR_FPB;        // first frame of this block's window

    const int tid  = threadIdx.x;
    const int lane = tid & 63;
    const int wid  = tid >> 6;          // 4 waves

    __shared__ int smem_idx[LR_FPB];    // frame -> phoneme (-1 = masked)
    __shared__ int wsum[LR_THREADS / 64];

    if (tid < LR_FPB) smem_idx[tid] = -1;

    // Each thread owns phonemes 2*tid and 2*tid+1.
    const int2 d2 = ((const int2*)(dur + b * LR_P))[tid];
    const int  e0 = d2.x, e1 = d2.y;
    int s = e0 + e1;

    // Inclusive wave scan over pair-sums (6 shuffle steps, no barriers).
    #pragma unroll
    for (int off = 1; off < 64; off <<= 1) {
        int u = __shfl_up(s, off, 64);
        if (lane >= off) s += u;
    }
    if (lane == 63) wsum[wid] = s;
    __syncthreads();

    int woff = 0, total = 0;
    #pragma unroll
    for (int i = 0; i < LR_THREADS / 64; ++i) {
        int w = wsum[i];
        woff  += (i < wid) ? w : 0;
        total += w;
    }
    const int ends1  = s + woff;        // inclusive end of phoneme 2*tid+1
    const int ends0  = ends1 - e1;      // inclusive end of phoneme 2*tid
    const int start0 = ends0 - e0;      // start of phoneme 2*tid

    // Scatter this thread's two phoneme intervals into the block window.
    {
        int lo = max(start0, base), hi = min(ends0, base + LR_FPB);
        for (int f = lo; f < hi; ++f) smem_idx[f - base] = 2 * tid;
        lo = max(ends0, base);  hi = min(ends1, base + LR_FPB);
        for (int f = lo; f < hi; ++f) smem_idx[f - base] = 2 * tid + 1;
    }
    if (c == 0 && tid == 0) mel_out[b] = (float)total;  // mel_len as float
    __syncthreads();

    // Gather + stream out: 12 float4 per thread, fully coalesced stores.
    const f32x4* xb    = x4 + (size_t)b * LR_P * LR_V4;
    f32x4*       ob    = out4 + ((size_t)b * LR_MAXLEN + base) * LR_V4;
    #pragma unroll
    for (int k = 0; k < LR_F4PT; ++k) {
        const unsigned j     = tid + k * LR_THREADS;   // [0, 3072)
        const unsigned frame = j / LR_V4;              // magic-mul
        const unsigned v     = j - frame * LR_V4;
        const int p = smem_idx[frame];                 // broadcast in 96-group
        f32x4 val;
        if (p >= 0) {
            val = xb[(unsigned)p * LR_V4 + v];
        } else {
            val = (f32x4){0.f, 0.f, 0.f, 0.f};
        }
        __builtin_nontemporal_store(val, &ob[j]);
    }
}

extern "C" void kernel_launch(void* const* d_in, const int* in_sizes, int n_in,
                              void* d_out, int out_size, void* d_ws, size_t ws_size,
                              hipStream_t stream)
{
    const float* x   = (const float*)d_in[0];  // [B][P][D] float32
    const int*   dur = (const int*)d_in[1];    // [B][P] int32
    // d_in[2] = max_len scalar (2048), compile-time constant here.

    float* out = (float*)d_out;                          // [B][MAXLEN][D]
    float* mel = out + (size_t)LR_B * LR_MAXLEN * LR_D;  // [B] float-encoded

    lr_fused<<<LR_GBLOCKS, LR_THREADS, 0, stream>>>(
        dur, (const f32x4*)x, (f32x4*)out, mel);
}